// Round 1
// baseline (20.916 us; speedup 1.0000x reference)
//
#include <hip/hip_runtime.h>
#include <hip/hip_bf16.h>

// Embedding gather: out[token, :] = weight[x[token], :]
// x: int32 [B*S] = [16384], weight: f32 [50257, 768], out: f32 [16384, 768]
// One block per token; 192 threads x float4 = 768 floats = one row.

__global__ void embed_gather_kernel(const int* __restrict__ x,
                                    const float4* __restrict__ w,
                                    float4* __restrict__ out,
                                    int dim4) {
    const int token = blockIdx.x;
    const int row = x[token];                    // wave-uniform scalar load
    const float4* __restrict__ src = w + (size_t)row * dim4;
    float4* __restrict__ dst = out + (size_t)token * dim4;
    for (int c = threadIdx.x; c < dim4; c += blockDim.x) {
        dst[c] = src[c];
    }
}

extern "C" void kernel_launch(void* const* d_in, const int* in_sizes, int n_in,
                              void* d_out, int out_size, void* d_ws, size_t ws_size,
                              hipStream_t stream) {
    const int* x = (const int*)d_in[0];
    const float* weight = (const float*)d_in[1];
    float* out = (float*)d_out;

    const int n_tokens = in_sizes[0];            // B*S = 16384
    const int dim = out_size / n_tokens;         // 768
    const int dim4 = dim / 4;                    // 192 float4 per row

    // 192 threads = 3 waves, exactly one float4 per lane per row.
    dim3 grid(n_tokens);
    dim3 block(dim4);
    embed_gather_kernel<<<grid, block, 0, stream>>>(
        x, (const float4*)weight, (float4*)out, dim4);
}

// Round 3
// 20.586 us; speedup vs baseline: 1.0160x; 1.0160x over previous
//
#include <hip/hip_runtime.h>
#include <hip/hip_bf16.h>

// Embedding gather: out[token, :] = weight[x[token], :]
// x: int32 [16384], weight: f32 [50257, 768], out: f32 [16384, 768]
// One wave per token row: 192 float4 = 64 lanes x 3 independent 16B loads
// -> 3 nontemporal 16B stores (output is write-once; keep weight in L3).

typedef float f32x4 __attribute__((ext_vector_type(4)));  // native vector: ok for nontemporal builtins

__global__ void __launch_bounds__(256)
embed_gather_kernel(const int* __restrict__ x,
                    const f32x4* __restrict__ w,
                    f32x4* __restrict__ out,
                    int n_tokens) {
    const int wave = threadIdx.x >> 6;     // 0..3
    const int lane = threadIdx.x & 63;
    const int tokens_per_iter = gridDim.x * 4;

    for (int token = blockIdx.x * 4 + wave; token < n_tokens; token += tokens_per_iter) {
        const int row = x[token];          // wave-uniform
        const f32x4* __restrict__ src = w + (size_t)row * 192;
        f32x4* __restrict__ dst = out + (size_t)token * 192;

        // 3 independent loads in flight per lane.
        f32x4 a = src[lane];
        f32x4 b = src[lane + 64];
        f32x4 c = src[lane + 128];

        __builtin_nontemporal_store(a, &dst[lane]);
        __builtin_nontemporal_store(b, &dst[lane + 64]);
        __builtin_nontemporal_store(c, &dst[lane + 128]);
    }
}

extern "C" void kernel_launch(void* const* d_in, const int* in_sizes, int n_in,
                              void* d_out, int out_size, void* d_ws, size_t ws_size,
                              hipStream_t stream) {
    const int* x = (const int*)d_in[0];
    const float* weight = (const float*)d_in[1];
    float* out = (float*)d_out;

    const int n_tokens = in_sizes[0];      // 16384

    // One wave per token, 4 waves per block -> exactly 1 iteration per wave.
    int blocks = (n_tokens + 3) / 4;       // 4096
    embed_gather_kernel<<<blocks, 256, 0, stream>>>(
        x, (const f32x4*)weight, (f32x4*)out, n_tokens);
}

// Round 4
// 20.211 us; speedup vs baseline: 1.0349x; 1.0185x over previous
//
#include <hip/hip_runtime.h>
#include <hip/hip_bf16.h>

// Embedding gather: out[token, :] = weight[x[token], :]
// x: int32 [16384], weight: f32 [50257, 768], out: f32 [16384, 768]
// 2 tokens per wave: both token ids loaded up front, then 6 independent
// 16B gather loads in flight, then 6 nontemporal stores.
// 2048 blocks x 256 threads = 8 blocks/CU = full 32-wave residency.

typedef float f32x4 __attribute__((ext_vector_type(4)));

__global__ void __launch_bounds__(256)
embed_gather_kernel(const int* __restrict__ x,
                    const f32x4* __restrict__ w,
                    f32x4* __restrict__ out,
                    int n_tokens) {
    const int wave = threadIdx.x >> 6;     // 0..3
    const int lane = threadIdx.x & 63;
    const int base = blockIdx.x * 8 + wave * 2;   // 8 tokens per block

    if (base + 1 < n_tokens) {
        // Both row ids first (independent scalar loads).
        const int r0 = x[base];
        const int r1 = x[base + 1];
        const f32x4* __restrict__ s0 = w + (size_t)r0 * 192;
        const f32x4* __restrict__ s1 = w + (size_t)r1 * 192;

        // 6 independent gather loads in flight.
        f32x4 a0 = s0[lane];
        f32x4 a1 = s0[lane + 64];
        f32x4 a2 = s0[lane + 128];
        f32x4 b0 = s1[lane];
        f32x4 b1 = s1[lane + 64];
        f32x4 b2 = s1[lane + 128];

        f32x4* __restrict__ dst = out + (size_t)base * 192;
        __builtin_nontemporal_store(a0, &dst[lane]);
        __builtin_nontemporal_store(a1, &dst[lane + 64]);
        __builtin_nontemporal_store(a2, &dst[lane + 128]);
        __builtin_nontemporal_store(b0, &dst[lane + 192]);
        __builtin_nontemporal_store(b1, &dst[lane + 256]);
        __builtin_nontemporal_store(b2, &dst[lane + 320]);
    } else if (base < n_tokens) {
        // Tail: single token (not hit for 16384, kept for generality).
        const int r0 = x[base];
        const f32x4* __restrict__ s0 = w + (size_t)r0 * 192;
        f32x4* __restrict__ dst = out + (size_t)base * 192;
        __builtin_nontemporal_store(s0[lane],       &dst[lane]);
        __builtin_nontemporal_store(s0[lane + 64],  &dst[lane + 64]);
        __builtin_nontemporal_store(s0[lane + 128], &dst[lane + 128]);
    }
}

extern "C" void kernel_launch(void* const* d_in, const int* in_sizes, int n_in,
                              void* d_out, int out_size, void* d_ws, size_t ws_size,
                              hipStream_t stream) {
    const int* x = (const int*)d_in[0];
    const float* weight = (const float*)d_in[1];
    float* out = (float*)d_out;

    const int n_tokens = in_sizes[0];      // 16384
    int blocks = (n_tokens + 7) / 8;       // 2048
    embed_gather_kernel<<<blocks, 256, 0, stream>>>(
        x, (const f32x4*)weight, (f32x4*)out, n_tokens);
}